// Round 2
// baseline (11.579 us; speedup 1.0000x reference)
//
#include <hip/hip_runtime.h>

// BPR loss: out = -(1/B) * sum_{b, t < x_len[b]} log_sigmoid(pos - neg) / x_len[b]
// B=32, T=100, N_ITEMS=100000, S=1 -> 3200 items, 6400 scattered gathers.
// One block, latency-bound. Strategy: 2 memory epochs (index loads, then
// gathers), fully unrolled K=4 items/thread, branch-free via weight=0.

#define B_     32
#define T_     100
#define N_     100000
#define NITEMS (B_ * T_)   // 3200
#define NT     1024
#define K      4           // ceil(3200/1024)

__global__ __launch_bounds__(NT) void bpr_loss_kernel(
    const float* __restrict__ output,
    const int*   __restrict__ labels,
    const int*   __restrict__ x_lens,
    const int*   __restrict__ neg_ids,
    float*       __restrict__ out)
{
    const int tid = threadIdx.x;

    // ---- Phase 1: all index loads issue together ----
    const float* rowp[K];
    int   lab[K], nid[K];
    float w[K];
#pragma unroll
    for (int k = 0; k < K; ++k) {
        const int  i     = tid + k * NT;
        const bool valid = (i < NITEMS);
        const int  ii    = valid ? i : 0;
        lab[k] = labels[ii];
        nid[k] = neg_ids[ii];          // S=1 -> flat [3200]
        const int b  = ii / T_;
        const int t  = ii - b * T_;
        const int xl = x_lens[b];
        w[k]    = (valid && t < xl) ? (1.0f / (float)xl) : 0.0f;
        rowp[k] = output + (size_t)ii * N_;
    }

    // ---- Phase 2: all 8 gathers issue together ----
    float pos[K], neg[K];
#pragma unroll
    for (int k = 0; k < K; ++k) {
        pos[k] = rowp[k][lab[k]];
        neg[k] = rowp[k][nid[k]];
    }

    // ---- Phase 3: compute ----
    float acc = 0.f;
#pragma unroll
    for (int k = 0; k < K; ++k) {
        const float x = pos[k] - neg[k];
        // stable log_sigmoid(x) = min(x,0) - log1p(exp(-|x|))
        acc += w[k] * (fminf(x, 0.f) - log1pf(expf(-fabsf(x))));
    }

    // ---- deterministic block reduction ----
    for (int off = 32; off > 0; off >>= 1)
        acc += __shfl_down(acc, off, 64);

    __shared__ float wsum[NT / 64];
    const int wid  = tid >> 6;
    const int lane = tid & 63;
    if (lane == 0) wsum[wid] = acc;
    __syncthreads();

    if (wid == 0) {
        float v = (lane < (NT / 64)) ? wsum[lane] : 0.f;
        for (int off = 8; off > 0; off >>= 1)
            v += __shfl_down(v, off, 64);
        if (lane == 0) out[0] = -v / (float)B_;
    }
}

extern "C" void kernel_launch(void* const* d_in, const int* in_sizes, int n_in,
                              void* d_out, int out_size, void* d_ws, size_t ws_size,
                              hipStream_t stream) {
    const float* output  = (const float*)d_in[0];
    const int*   labels  = (const int*)  d_in[1];
    const int*   x_lens  = (const int*)  d_in[2];
    const int*   neg_ids = (const int*)  d_in[3];
    // d_in[4] = uids, unused
    float* out = (float*)d_out;

    bpr_loss_kernel<<<1, NT, 0, stream>>>(output, labels, x_lens, neg_ids, out);
}

// Round 3
// 11.310 us; speedup vs baseline: 1.0238x; 1.0238x over previous
//
#include <hip/hip_runtime.h>

// BPR loss: out = -(1/B) * sum_{b, t < x_len[b]} log_sigmoid(pos - neg) / x_len[b]
// B=32, T=100, N_ITEMS=100000, S=1 -> 3200 items, 6400 scattered gathers from
// a 1.28 GB tensor. Latency-bound: spread misses over 50 CUs (kernel A),
// then one-wave deterministic final reduce (kernel B).

#define B_     32
#define T_     100
#define N_     100000
#define NITEMS (B_ * T_)        // 3200
#define NBLK   (NITEMS / 64)    // 50 blocks x 64 threads, 1 item/thread

__global__ __launch_bounds__(64) void bpr_partial_kernel(
    const float* __restrict__ output,
    const int*   __restrict__ labels,
    const int*   __restrict__ x_lens,
    const int*   __restrict__ neg_ids,
    float*       __restrict__ partials)
{
    const int i = blockIdx.x * 64 + threadIdx.x;   // < 3200 always

    // index loads (one epoch)
    const int b   = i / T_;
    const int t   = i - b * T_;
    const int lab = labels[i];
    const int nid = neg_ids[i];     // S=1 -> flat [3200]
    const int xl  = x_lens[b];

    // gathers (second epoch; both issue together)
    const float* row = output + (size_t)i * N_;
    const float pos = row[lab];
    const float neg = row[nid];

    const float x = pos - neg;
    // stable log_sigmoid(x) = min(x,0) - log1p(exp(-|x|))
    float v = (t < xl ? 1.0f / (float)xl : 0.0f)
              * (fminf(x, 0.f) - log1pf(expf(-fabsf(x))));

    // single-wave reduction (block == 1 wave)
    for (int off = 32; off > 0; off >>= 1)
        v += __shfl_down(v, off, 64);

    if (threadIdx.x == 0) partials[blockIdx.x] = v;
}

__global__ __launch_bounds__(64) void bpr_final_kernel(
    const float* __restrict__ partials,
    float*       __restrict__ out)
{
    const int tid = threadIdx.x;
    float v = (tid < NBLK) ? partials[tid] : 0.f;
    for (int off = 32; off > 0; off >>= 1)
        v += __shfl_down(v, off, 64);
    if (tid == 0) out[0] = -v / (float)B_;
}

extern "C" void kernel_launch(void* const* d_in, const int* in_sizes, int n_in,
                              void* d_out, int out_size, void* d_ws, size_t ws_size,
                              hipStream_t stream) {
    const float* output  = (const float*)d_in[0];
    const int*   labels  = (const int*)  d_in[1];
    const int*   x_lens  = (const int*)  d_in[2];
    const int*   neg_ids = (const int*)  d_in[3];
    // d_in[4] = uids, unused
    float* out      = (float*)d_out;
    float* partials = (float*)d_ws;

    bpr_partial_kernel<<<NBLK, 64, 0, stream>>>(output, labels, x_lens, neg_ids, partials);
    bpr_final_kernel<<<1, 64, 0, stream>>>(partials, out);
}